// Round 5
// baseline (127.770 us; speedup 1.0000x reference)
//
#include <hip/hip_runtime.h>
#include <hip/hip_bf16.h>
#include <math.h>

#define B 512
#define M 24
#define F 128
#define NRBF 20
#define CUTOFF 5.0f
#define NPAIR (M * M)   // 576

// One block per molecule, 512 threads, 2 blocks/CU (entire grid resident).
// __launch_bounds__(512, 2): rounds 2-4 showed hipcc capping at 64 VGPRs
// under (512,4) (spill traffic: FETCH 1.2->37MB). Under (512,2) the VGPR
// budget is >=128 for either interpretation of arg2, which is all the
// occupancy the 55KB/block LDS footprint permits anyway (2 blocks/CU).
// Phase 3 is branchless (masked pairs have r1=r2=c2=mask=0 so all terms
// vanish), keeps the 40 loop-invariant Wf weights in VGPRs, and reads
// edge record + phi from LDS per pair (pipelined, no dependent branch).
// RBF: r_n = sin(n*k*d)/d via two Chebyshev chains r_{n+2}=c2*r_n-r_{n-2}.
// The dv_v * v term of the reference is identically zero since v^0 = 0.

__global__ __launch_bounds__(512, 2) void painn_kernel(
    const int* __restrict__ atoms,
    const float* __restrict__ apos,
    const float* __restrict__ emb,
    const float* __restrict__ W1, const float* __restrict__ b1,
    const float* __restrict__ W2, const float* __restrict__ b2,
    const float* __restrict__ Wf, const float* __restrict__ bf,
    float* __restrict__ out)
{
    __shared__ __attribute__((aligned(16))) float sSH[M][F];        // s, later h
    __shared__ __attribute__((aligned(16))) float sPhi[M][F][2];    // (phi0, phi2)
    __shared__ __attribute__((aligned(16))) float sEdge[NPAIR][8];  // rx,ry,rz,mask,r1,r2,c2,0
    __shared__ __attribute__((aligned(16))) float sPos[M][4];
    __shared__ __attribute__((aligned(16))) float sBf[2 * F];       // bf[0:128] | bf[256:384]

    const int tid = threadIdx.x;
    const int b = blockIdx.x;

    // ---- Phase 0: loads -------------------------------------------------
    for (int idx = tid; idx < M * (F / 4); idx += 512) {
        int node = idx >> 5;
        int f4   = idx & 31;
        int a = atoms[b * M + node];
        float4 v = reinterpret_cast<const float4*>(emb + (size_t)a * F)[f4];
        reinterpret_cast<float4*>(&sSH[node][0])[f4] = v;
    }
    if (tid < M * 3) {
        sPos[tid / 3][tid % 3] = apos[(size_t)b * M * 3 + tid];
    }
    if (tid >= 256 && tid < 512) {
        int t = tid - 256;
        sBf[t] = bf[t < F ? t : t + F];
    }
    __syncthreads();

    // ---- Phase G: geometry + trig seeds (all-zero when masked) ---------
    for (int p = tid; p < NPAIR; p += 512) {
        int i = p / M;
        int j = p - i * M;
        float dx = sPos[i][0] - sPos[j][0];
        float dy = sPos[i][1] - sPos[j][1];
        float dz = sPos[i][2] - sPos[j][2];
        float d = sqrtf(dx * dx + dy * dy + dz * dz);
        bool m = (d < CUTOFF) && (i != j);
        float4 g4 = make_float4(0.f, 0.f, 0.f, 0.f);
        float4 t4 = make_float4(0.f, 0.f, 0.f, 0.f);
        if (m) {
            float inv = 1.0f / d;
            g4 = make_float4(dx * inv, dy * inv, dz * inv, 1.0f);
            const float k = 3.14159265358979323846f / CUTOFF;
            float s1, c1;
            __sincosf(k * d, &s1, &c1);
            t4.x = s1 * inv;                          // sin(kd)/d
            t4.y = 2.0f * s1 * c1 * inv;              // sin(2kd)/d
            t4.z = 2.0f * (2.0f * c1 * c1 - 1.0f);    // 2*cos(2kd)
        }
        reinterpret_cast<float4*>(&sEdge[p][0])[0] = g4;
        reinterpret_cast<float4*>(&sEdge[p][4])[0] = t4;
    }

    // ---- Phase 1: h = silu(s @ W1 + b1) --------------------------------
    {
        const int k = tid & 127;
        const int q = tid >> 7;
        float acc[6];
#pragma unroll
        for (int t = 0; t < 6; ++t) acc[t] = 0.f;
#pragma unroll 4
        for (int f = 0; f < F; ++f) {
            float w = W1[(size_t)f * F + k];
#pragma unroll
            for (int t = 0; t < 6; ++t) acc[t] += sSH[q * 6 + t][f] * w;
        }
        float bk = b1[k];
        float h[6];
#pragma unroll
        for (int t = 0; t < 6; ++t) {
            float x = acc[t] + bk;
            h[t] = x / (1.0f + __expf(-x));
        }
        __syncthreads();   // s reads done; edge writes become visible
#pragma unroll
        for (int t = 0; t < 6; ++t) sSH[q * 6 + t][k] = h[t];
    }
    __syncthreads();

    // ---- Phase 2: phi chunks 0 and 2 -> sPhi[node][f][{0,1}] -----------
    {
        const int c2 = tid & 255;
        const int hh = tid >> 8;
        const int wcol = (c2 < F) ? c2 : (c2 + F);
        float acc[12];
#pragma unroll
        for (int t = 0; t < 12; ++t) acc[t] = 0.f;
#pragma unroll 4
        for (int f = 0; f < F; ++f) {
            float w = W2[(size_t)f * (3 * F) + wcol];
#pragma unroll
            for (int t = 0; t < 12; ++t) acc[t] += sSH[hh * 12 + t][f] * w;
        }
        float bb = b2[wcol];
        const int fcol = (c2 < F) ? c2 : (c2 - F);
        const int lane = (c2 < F) ? 0 : 1;
#pragma unroll
        for (int t = 0; t < 12; ++t) sPhi[hh * 12 + t][fcol][lane] = acc[t] + bb;
    }
    __syncthreads();

    // ---- Phase 3: edge aggregation (branchless, Wf resident) ------------
    const int f = tid & 127;
    const int iq = tid >> 7;    // 0..3

    float wf0[NRBF], wf2[NRBF];
#pragma unroll
    for (int n = 0; n < NRBF; ++n) {
        wf0[n] = Wf[(size_t)n * (3 * F) + f];
        wf2[n] = Wf[(size_t)n * (3 * F) + 2 * F + f];
    }
    const float bf0 = sBf[f];
    const float bf2 = sBf[F + f];

#pragma unroll 1
    for (int ii = 0; ii < 6; ++ii) {
        const int i = iq * 6 + ii;
        float ds = 0.f, dvx = 0.f, dvy = 0.f, dvz = 0.f;
        const float* ep = &sEdge[i * M][0];
#pragma unroll
        for (int j = 0; j < M; ++j) {
            float4 g = *reinterpret_cast<const float4*>(ep + j * 8);
            float4 t = *reinterpret_cast<const float4*>(ep + j * 8 + 4);
            float2 ph = *reinterpret_cast<const float2*>(&sPhi[j][f][0]);
            float a0 = t.x, b0 = t.y, c2 = t.z;
            float w0 = bf0 * g.w + a0 * wf0[0] + b0 * wf0[1];
            float w2 = bf2 * g.w + a0 * wf2[0] + b0 * wf2[1];
            float a1 = c2 * a0 + a0;       // sin3/d
            float b1v = c2 * b0;           // sin4/d
            w0 += a1 * wf0[2] + b1v * wf0[3];
            w2 += a1 * wf2[2] + b1v * wf2[3];
#pragma unroll
            for (int n = 2; n < 10; ++n) {
                float a2 = c2 * a1 - a0;   // odd chain
                float b2 = c2 * b1v - b0;  // even chain
                w0 += a2 * wf0[2 * n] + b2 * wf0[2 * n + 1];
                w2 += a2 * wf2[2 * n] + b2 * wf2[2 * n + 1];
                a0 = a1; a1 = a2; b0 = b1v; b1v = b2;
            }
            ds  += w0 * ph.x;
            float m2 = w2 * ph.y;
            dvx += m2 * g.x;
            dvy += m2 * g.y;
            dvz += m2 * g.z;
        }
        const int node = b * M + i;
        const int a = atoms[node];
        float* o = out + (size_t)node * (4 * F);
        o[f] = emb[(size_t)a * F + f] + ds;
        o[F + 3 * f + 0] = dvx;
        o[F + 3 * f + 1] = dvy;
        o[F + 3 * f + 2] = dvz;
    }
}

extern "C" void kernel_launch(void* const* d_in, const int* in_sizes, int n_in,
                              void* d_out, int out_size, void* d_ws, size_t ws_size,
                              hipStream_t stream) {
    const int*   atoms = (const int*)d_in[0];
    const float* apos  = (const float*)d_in[1];
    // d_in[2] = graph_indexes (unused; batch structure is the fixed [B,M] layout)
    const float* emb = (const float*)d_in[3];
    const float* W1  = (const float*)d_in[4];
    const float* b1  = (const float*)d_in[5];
    const float* W2  = (const float*)d_in[6];
    const float* b2  = (const float*)d_in[7];
    const float* Wf  = (const float*)d_in[8];
    const float* bf  = (const float*)d_in[9];
    float* out = (float*)d_out;

    painn_kernel<<<B, 512, 0, stream>>>(atoms, apos, emb, W1, b1, W2, b2, Wf, bf, out);
}

// Round 6
// 37.637 us; speedup vs baseline: 3.3948x; 3.3948x over previous
//
#include <hip/hip_runtime.h>
#include <hip/hip_bf16.h>
#include <math.h>

#define B 512
#define M 24
#define F 128
#define NRBF 20
#define CUTOFF 5.0f

// ---- MFMA structure (one block = one molecule, 512 thr = 8 waves) ----
// P1: h   = silu(s @ W1 + b1)            [32pad x 128] @ [128 x 128]   MFMA
// P2: phi = h @ W2 + b2 (cols 0:F,2F:3F) [32pad x 128] @ [128 x 256]   MFMA
// P3: edge filter C = rbf @ Wf            [768 x 32pad] @ [32 x 256]   MFMA
//     rows of P3 = i*32 + j (j 24..31 and masked pairs are all-zero rows)
//     consume in-register: ds[i][f]   = sum_j (C0 + bf0*mask)*phi0[j][f]
//                          dv[i][f][c]= sum_j (C2 + bf2*mask)*phi2[j][f]*rhat[c]
// Fragment layouts (v_mfma_f32_16x16x32_bf16):
//   C/D: col = lane&15, row = (lane>>4)*4 + reg            [m89-verified]
//   A:   row = lane&15, k = (e>>2)*16 + 4*(lane>>4)+(e&3)  [m162 tr-read]
//   B:   col = lane&15, k = same mapping                   (e = 0..7)
// dv_v * v term of the reference is identically zero (v^0 = 0).

typedef __attribute__((ext_vector_type(8))) short short8;
typedef __attribute__((ext_vector_type(4))) float f32x4;

#define KIDX(g, e) ((((e) >> 2) << 4) + 4 * (g) + ((e) & 3))

__device__ __forceinline__ unsigned f2bf(float x) {
    unsigned u = __builtin_bit_cast(unsigned, x);
    return (u + 0x7FFFu + ((u >> 16) & 1u)) >> 16;   // RNE bf16
}

__device__ __forceinline__ short8 pack_frag(unsigned u0, unsigned u1,
                                            unsigned u2, unsigned u3) {
    uint4 t = make_uint4(u0, u1, u2, u3);
    return __builtin_bit_cast(short8, t);
}

// B-fragment from a global fp32 row-major matrix W[ld columns]
__device__ __forceinline__ short8 load_wfrag(const float* __restrict__ W, int ld,
                                             int col, int kbase, int kvalid, int g) {
    unsigned u[4];
#pragma unroll
    for (int q = 0; q < 4; ++q) {
        int k0 = kbase + KIDX(g, 2 * q);
        int k1 = kbase + KIDX(g, 2 * q + 1);
        float f0 = (k0 < kvalid) ? W[(size_t)k0 * ld + col] : 0.f;
        float f1 = (k1 < kvalid) ? W[(size_t)k1 * ld + col] : 0.f;
        u[q] = f2bf(f0) | (f2bf(f1) << 16);
    }
    return pack_frag(u[0], u[1], u[2], u[3]);
}

// A-fragment from LDS bf16 matrix with row stride `ldsh` shorts (k contiguous)
__device__ __forceinline__ short8 load_afrag(const short* sp, int row, int ldsh,
                                             int kbase, int g) {
    const short* p = sp + row * ldsh + kbase + 4 * g;
    uint2 lo = *(const uint2*)(p);
    uint2 hi = *(const uint2*)(p + 16);
    return pack_frag(lo.x, lo.y, hi.x, hi.y);
}

__global__ __launch_bounds__(512, 2) void painn_kernel(
    const int* __restrict__ atoms,
    const float* __restrict__ apos,
    const float* __restrict__ emb,
    const float* __restrict__ W1, const float* __restrict__ b1,
    const float* __restrict__ W2, const float* __restrict__ b2,
    const float* __restrict__ Wf, const float* __restrict__ bf,
    float* __restrict__ out)
{
    __shared__ __attribute__((aligned(16))) short sH[32 * 136];       // s then h, bf16
    __shared__ __attribute__((aligned(16))) float sPhi[32][F][2];     // phi0, phi2 fp32
    __shared__ __attribute__((aligned(16))) short sA[8 * 32 * 40];    // rbf bf16, 1 i-chunk
    __shared__ __attribute__((aligned(16))) float4 sGeo[M * 32];      // rhat.xyz, mask
    __shared__ __attribute__((aligned(16))) float sPos[M][4];

    const int tid  = threadIdx.x;
    const int b    = blockIdx.x;
    const int wid  = tid >> 6;
    const int lane = tid & 63;
    const int g    = lane >> 4;
    const int lrow = lane & 15;
    const int f2   = wid * 16 + lrow;          // this wave's feature column 0..127

    // ---- P0: s -> sH (bf16), zero pad rows, positions -------------------
    for (int idx = tid; idx < M * (F / 4); idx += 512) {
        int node = idx >> 5;
        int f4 = idx & 31;
        int a = atoms[b * M + node];
        float4 v = reinterpret_cast<const float4*>(emb + (size_t)a * F)[f4];
        unsigned u0 = f2bf(v.x) | (f2bf(v.y) << 16);
        unsigned u1 = f2bf(v.z) | (f2bf(v.w) << 16);
        *reinterpret_cast<uint2*>(&sH[node * 136 + f4 * 4]) = make_uint2(u0, u1);
    }
    // zero rows 24..31 of sH (8 rows x 136 shorts = 544 u32)
    for (int t = tid; t < 544; t += 512)
        reinterpret_cast<unsigned*>(sH)[24 * 68 + t] = 0u;   // 24*136 shorts = 24*68 u32
    if (tid < M * 3) sPos[tid / 3][tid % 3] = apos[(size_t)b * M * 3 + tid];
    __syncthreads();

    // ---- G: geometry (rhat, mask) for all 24x32 slots -------------------
    for (int p = tid; p < M * 32; p += 512) {
        int i = p >> 5, j = p & 31;
        float4 g4 = make_float4(0.f, 0.f, 0.f, 0.f);
        if (j < M) {
            float dx = sPos[i][0] - sPos[j][0];
            float dy = sPos[i][1] - sPos[j][1];
            float dz = sPos[i][2] - sPos[j][2];
            float d = sqrtf(dx * dx + dy * dy + dz * dz);
            if (d < CUTOFF && i != j) {
                float inv = 1.0f / d;
                g4 = make_float4(dx * inv, dy * inv, dz * inv, 1.0f);
            }
        }
        sGeo[p] = g4;
    }

    // ---- P1: h = silu(s @ W1 + b1), MFMA ------------------------------
    {
        float b1v = b1[f2];
        f32x4 c[2] = {{0.f, 0.f, 0.f, 0.f}, {0.f, 0.f, 0.f, 0.f}};
#pragma unroll
        for (int ks = 0; ks < 4; ++ks) {
            short8 bfrag = load_wfrag(W1, F, f2, ks * 32, 128, g);
            short8 a0 = load_afrag(sH, lrow, 136, ks * 32, g);
            short8 a1 = load_afrag(sH, 16 + lrow, 136, ks * 32, g);
            c[0] = __builtin_amdgcn_mfma_f32_16x16x32_bf16(a0, bfrag, c[0], 0, 0, 0);
            c[1] = __builtin_amdgcn_mfma_f32_16x16x32_bf16(a1, bfrag, c[1], 0, 0, 0);
        }
        __syncthreads();   // all s reads done before overwriting sH with h
#pragma unroll
        for (int rt = 0; rt < 2; ++rt)
#pragma unroll
            for (int r = 0; r < 4; ++r) {
                int row = rt * 16 + g * 4 + r;
                float x = c[rt][r] + b1v;
                float h = x / (1.0f + __expf(-x));
                sH[row * 136 + f2] = (short)f2bf(h);
            }
    }
    __syncthreads();

    // ---- P2: phi = h @ W2 + b2 (chunks 0 and 2), MFMA -----------------
#pragma unroll
    for (int half = 0; half < 2; ++half) {
        int wcol = half ? (256 + f2) : f2;      // W2 / b2 column
        float b2v = b2[wcol];
        f32x4 c[2] = {{0.f, 0.f, 0.f, 0.f}, {0.f, 0.f, 0.f, 0.f}};
#pragma unroll
        for (int ks = 0; ks < 4; ++ks) {
            short8 bfrag = load_wfrag(W2, 3 * F, wcol, ks * 32, 128, g);
            short8 a0 = load_afrag(sH, lrow, 136, ks * 32, g);
            short8 a1 = load_afrag(sH, 16 + lrow, 136, ks * 32, g);
            c[0] = __builtin_amdgcn_mfma_f32_16x16x32_bf16(a0, bfrag, c[0], 0, 0, 0);
            c[1] = __builtin_amdgcn_mfma_f32_16x16x32_bf16(a1, bfrag, c[1], 0, 0, 0);
        }
#pragma unroll
        for (int rt = 0; rt < 2; ++rt)
#pragma unroll
            for (int r = 0; r < 4; ++r) {
                int row = rt * 16 + g * 4 + r;
                sPhi[row][f2][half] = c[rt][r] + b2v;
            }
    }
    __syncthreads();

    // ---- P3: edge filter GEMM + consume, per 8-molecule-row chunk ------
    short8 wfrag0 = load_wfrag(Wf, 3 * F, f2, 0, NRBF, g);
    short8 wfrag2 = load_wfrag(Wf, 3 * F, 256 + f2, 0, NRBF, g);
    const float bf0v = bf[f2];
    const float bf2v = bf[256 + f2];
    const float kth = 3.14159265358979323846f / CUTOFF;

    for (int ic = 0; ic < 3; ++ic) {
        // produce rbf rows for i = ic*8 .. ic*8+7 (256 producer threads)
        if (tid < 256) {
            int il = tid >> 5, j = tid & 31;
            int i = ic * 8 + il;
            unsigned pk[16];
#pragma unroll
            for (int q = 0; q < 16; ++q) pk[q] = 0u;
            bool valid = false;
            if (j < M && j != i) {
                float dx = sPos[i][0] - sPos[j][0];
                float dy = sPos[i][1] - sPos[j][1];
                float dz = sPos[i][2] - sPos[j][2];
                float d = sqrtf(dx * dx + dy * dy + dz * dz);
                if (d < CUTOFF) {
                    valid = true;
                    float inv = 1.0f / d;
                    float s1, c1;
                    __sincosf(kth * d, &s1, &c1);
                    float cc = 2.0f * c1;
                    float vp = s1 * inv;             // sin(1*th)/d
                    float vc = cc * s1 * 0.5f * 2.0f * inv; // sin(2*th)/d = 2 s1 c1 /d
                    vc = 2.0f * s1 * c1 * inv;
                    pk[0] = f2bf(vp) | (f2bf(vc) << 16);
#pragma unroll
                    for (int q = 1; q < 10; ++q) {
                        float v3 = cc * vc - vp;     // v_{2q+1}
                        float v4 = cc * v3 - vc;     // v_{2q+2}
                        pk[q] = f2bf(v3) | (f2bf(v4) << 16);
                        vp = v3; vc = v4;
                    }
                }
            }
            (void)valid;
            short* rp = &sA[(il * 32 + j) * 40];
#pragma unroll
            for (int q = 0; q < 8; ++q)
                *reinterpret_cast<uint2*>(rp + q * 4) = make_uint2(pk[2 * q], pk[2 * q + 1]);
        }
        __syncthreads();

        // each wave: 8 i's x (2 row-tiles x 2 chunks) MFMA + consume
        for (int il = 0; il < 8; ++il) {
            const int i = ic * 8 + il;
            float s0 = 0.f, ax = 0.f, ay = 0.f, az = 0.f;
#pragma unroll
            for (int rt = 0; rt < 2; ++rt) {
                short8 afr = load_afrag(sA, il * 32 + rt * 16 + lrow, 40, 0, g);
                f32x4 z4 = {0.f, 0.f, 0.f, 0.f};
                f32x4 c0 = __builtin_amdgcn_mfma_f32_16x16x32_bf16(afr, wfrag0, z4, 0, 0, 0);
                f32x4 c2 = __builtin_amdgcn_mfma_f32_16x16x32_bf16(afr, wfrag2, z4, 0, 0, 0);
#pragma unroll
                for (int r = 0; r < 4; ++r) {
                    int j = rt * 16 + g * 4 + r;
                    float4 ge = sGeo[i * 32 + j];
                    float ph0 = sPhi[j][f2][0];
                    float ph2 = sPhi[j][f2][1];
                    float t0 = fmaf(bf0v, ge.w, c0[r]);
                    s0 = fmaf(t0, ph0, s0);
                    float t2 = fmaf(bf2v, ge.w, c2[r]);
                    float m2 = t2 * ph2;
                    ax = fmaf(m2, ge.x, ax);
                    ay = fmaf(m2, ge.y, ay);
                    az = fmaf(m2, ge.z, az);
                }
            }
            // reduce over the 4 lane-groups (j coverage)
            s0 += __shfl_xor(s0, 16); s0 += __shfl_xor(s0, 32);
            ax += __shfl_xor(ax, 16); ax += __shfl_xor(ax, 32);
            ay += __shfl_xor(ay, 16); ay += __shfl_xor(ay, 32);
            az += __shfl_xor(az, 16); az += __shfl_xor(az, 32);
            if (lane < 16) {
                const int node = b * M + i;
                const int a = atoms[node];
                float embv = emb[(size_t)a * F + f2];
                float* o = out + (size_t)node * (4 * F);
                o[f2] = embv + s0;
                o[F + 3 * f2 + 0] = ax;
                o[F + 3 * f2 + 1] = ay;
                o[F + 3 * f2 + 2] = az;
            }
        }
        __syncthreads();   // protect sA before next chunk's produce
    }
}

extern "C" void kernel_launch(void* const* d_in, const int* in_sizes, int n_in,
                              void* d_out, int out_size, void* d_ws, size_t ws_size,
                              hipStream_t stream) {
    const int*   atoms = (const int*)d_in[0];
    const float* apos  = (const float*)d_in[1];
    // d_in[2] = graph_indexes (unused; batch structure is the fixed [B,M] layout)
    const float* emb = (const float*)d_in[3];
    const float* W1  = (const float*)d_in[4];
    const float* b1  = (const float*)d_in[5];
    const float* W2  = (const float*)d_in[6];
    const float* b2  = (const float*)d_in[7];
    const float* Wf  = (const float*)d_in[8];
    const float* bf  = (const float*)d_in[9];
    float* out = (float*)d_out;

    painn_kernel<<<B, 512, 0, stream>>>(atoms, apos, emb, W1, b1, W2, b2, Wf, bf, out);
}

// Round 7
// 36.124 us; speedup vs baseline: 3.5369x; 1.0419x over previous
//
#include <hip/hip_runtime.h>
#include <hip/hip_bf16.h>
#include <hip/hip_fp16.h>
#include <math.h>

#define B 512
#define M 24
#define F 128
#define NRBF 20
#define CUTOFF 5.0f
#define SA_LD 44   // shorts per rbf row: 32 k-slots + 12 pad (88B, 22dw -> 2-way banks)

// ---- MFMA structure (one block = one molecule, 512 thr = 8 waves) ----
// P1: h   = silu(s @ W1 + b1)            [32pad x 128] @ [128 x 128]   MFMA
// P2: phi = h @ W2 + b2 (cols 0:F,2F:3F) [32pad x 128] @ [128 x 256]   MFMA
// P3: edge filter C = rbf_ext @ Wf_ext per 8-i chunk                   MFMA
//     rbf_ext k-slots: 0..19 = sin(nkd)/d, 20 = mask(1.0), 21..31 = 0
//     Wf_ext  row 20 = bf  -> C = (rbf@Wf + bf) * mask  (exact, branch-free:
//     invalid pairs are all-zero rows -> C = 0 -> kills garbage-phi terms)
//     consume: ds[i][f] = sum_j C0*phi0[j][f]; dv = sum_j C2*phi2[j][f]*rhat
//     phi[j][f2] hoisted to 16 registers/lane (static idx); rhat as half4.
// Fragment layouts (v_mfma_f32_16x16x32_bf16):
//   C/D: col = lane&15, row = (lane>>4)*4 + reg            [m89-verified]
//   A/B: row/col = lane&15, k = (e>>2)*16 + 4*(lane>>4)+(e&3)
// dv_v * v term of the reference is identically zero (v^0 = 0).

typedef __attribute__((ext_vector_type(8))) short short8;
typedef __attribute__((ext_vector_type(4))) float f32x4;

#define KIDX(g, e) ((((e) >> 2) << 4) + 4 * (g) + ((e) & 3))

__device__ __forceinline__ unsigned f2bf(float x) {
    unsigned u = __builtin_bit_cast(unsigned, x);
    return (u + 0x7FFFu + ((u >> 16) & 1u)) >> 16;   // RNE bf16
}
__device__ __forceinline__ unsigned f2h(float x) {
    __half h = __float2half(x);
    return (unsigned)__builtin_bit_cast(unsigned short, h);
}

__device__ __forceinline__ short8 pack_frag(unsigned u0, unsigned u1,
                                            unsigned u2, unsigned u3) {
    uint4 t = make_uint4(u0, u1, u2, u3);
    return __builtin_bit_cast(short8, t);
}

// B-fragment from a global fp32 row-major matrix W[ld columns]
__device__ __forceinline__ short8 load_wfrag(const float* __restrict__ W, int ld,
                                             int col, int kbase, int kvalid, int g) {
    unsigned u[4];
#pragma unroll
    for (int q = 0; q < 4; ++q) {
        int k0 = kbase + KIDX(g, 2 * q);
        int k1 = kbase + KIDX(g, 2 * q + 1);
        float f0 = (k0 < kvalid) ? W[(size_t)k0 * ld + col] : 0.f;
        float f1 = (k1 < kvalid) ? W[(size_t)k1 * ld + col] : 0.f;
        u[q] = f2bf(f0) | (f2bf(f1) << 16);
    }
    return pack_frag(u[0], u[1], u[2], u[3]);
}

// B-fragment for the extended edge filter: rows 0..19 = Wf, row 20 = bf, rest 0
__device__ __forceinline__ short8 load_wffrag(const float* __restrict__ Wf,
                                              const float* __restrict__ bfv,
                                              int col, int g) {
    unsigned u[4];
#pragma unroll
    for (int q = 0; q < 4; ++q) {
        int k0 = KIDX(g, 2 * q);
        int k1 = KIDX(g, 2 * q + 1);
        float f0 = (k0 < NRBF) ? Wf[(size_t)k0 * (3 * F) + col]
                               : (k0 == NRBF ? bfv[col] : 0.f);
        float f1 = (k1 < NRBF) ? Wf[(size_t)k1 * (3 * F) + col]
                               : (k1 == NRBF ? bfv[col] : 0.f);
        u[q] = f2bf(f0) | (f2bf(f1) << 16);
    }
    return pack_frag(u[0], u[1], u[2], u[3]);
}

// A-fragment from LDS bf16 matrix with row stride `ldsh` shorts (k contiguous)
__device__ __forceinline__ short8 load_afrag(const short* sp, int row, int ldsh,
                                             int kbase, int g) {
    const short* p = sp + row * ldsh + kbase + 4 * g;
    uint2 lo = *(const uint2*)(p);
    uint2 hi = *(const uint2*)(p + 16);
    return pack_frag(lo.x, lo.y, hi.x, hi.y);
}

__global__ __launch_bounds__(512, 2) void painn_kernel(
    const int* __restrict__ atoms,
    const float* __restrict__ apos,
    const float* __restrict__ emb,
    const float* __restrict__ W1, const float* __restrict__ b1,
    const float* __restrict__ W2, const float* __restrict__ b2,
    const float* __restrict__ Wf, const float* __restrict__ bf,
    float* __restrict__ out)
{
    __shared__ __attribute__((aligned(16))) short sH[32 * 136];       // s then h, bf16
    __shared__ __attribute__((aligned(16))) float sPhi[32][F][2];     // phi0, phi2 fp32
    __shared__ __attribute__((aligned(16))) short sA[8 * 32 * SA_LD]; // rbf_ext bf16
    __shared__ __attribute__((aligned(16))) short sGeoH[8 * 32 * 4];  // rhat half4
    __shared__ __attribute__((aligned(16))) float sPos[M][4];

    const int tid  = threadIdx.x;
    const int b    = blockIdx.x;
    const int wid  = tid >> 6;
    const int lane = tid & 63;
    const int g    = lane >> 4;
    const int lrow = lane & 15;
    const int f2   = wid * 16 + lrow;          // this wave's feature column 0..127

    // ---- P0: s -> sH (bf16), zero pad rows, positions -------------------
    for (int idx = tid; idx < M * (F / 4); idx += 512) {
        int node = idx >> 5;
        int f4 = idx & 31;
        int a = atoms[b * M + node];
        float4 v = reinterpret_cast<const float4*>(emb + (size_t)a * F)[f4];
        unsigned u0 = f2bf(v.x) | (f2bf(v.y) << 16);
        unsigned u1 = f2bf(v.z) | (f2bf(v.w) << 16);
        *reinterpret_cast<uint2*>(&sH[node * 136 + f4 * 4]) = make_uint2(u0, u1);
    }
    for (int t = tid; t < 544; t += 512)
        reinterpret_cast<unsigned*>(sH)[24 * 68 + t] = 0u;
    if (tid < M * 3) sPos[tid / 3][tid % 3] = apos[(size_t)b * M * 3 + tid];
    __syncthreads();

    // ---- P1: h = silu(s @ W1 + b1), MFMA ------------------------------
    {
        float b1v = b1[f2];
        f32x4 c[2] = {{0.f, 0.f, 0.f, 0.f}, {0.f, 0.f, 0.f, 0.f}};
#pragma unroll
        for (int ks = 0; ks < 4; ++ks) {
            short8 bfrag = load_wfrag(W1, F, f2, ks * 32, 128, g);
            short8 a0 = load_afrag(sH, lrow, 136, ks * 32, g);
            short8 a1 = load_afrag(sH, 16 + lrow, 136, ks * 32, g);
            c[0] = __builtin_amdgcn_mfma_f32_16x16x32_bf16(a0, bfrag, c[0], 0, 0, 0);
            c[1] = __builtin_amdgcn_mfma_f32_16x16x32_bf16(a1, bfrag, c[1], 0, 0, 0);
        }
        __syncthreads();   // all s reads done before overwriting sH with h
#pragma unroll
        for (int rt = 0; rt < 2; ++rt)
#pragma unroll
            for (int r = 0; r < 4; ++r) {
                int row = rt * 16 + g * 4 + r;
                float x = c[rt][r] + b1v;
                float h = x / (1.0f + __expf(-x));
                sH[row * 136 + f2] = (short)f2bf(h);
            }
    }
    __syncthreads();

    // ---- P2: phi = h @ W2 + b2 (chunks 0 and 2), MFMA -----------------
#pragma unroll
    for (int half = 0; half < 2; ++half) {
        int wcol = half ? (256 + f2) : f2;
        float b2v = b2[wcol];
        f32x4 c[2] = {{0.f, 0.f, 0.f, 0.f}, {0.f, 0.f, 0.f, 0.f}};
#pragma unroll
        for (int ks = 0; ks < 4; ++ks) {
            short8 bfrag = load_wfrag(W2, 3 * F, wcol, ks * 32, 128, g);
            short8 a0 = load_afrag(sH, lrow, 136, ks * 32, g);
            short8 a1 = load_afrag(sH, 16 + lrow, 136, ks * 32, g);
            c[0] = __builtin_amdgcn_mfma_f32_16x16x32_bf16(a0, bfrag, c[0], 0, 0, 0);
            c[1] = __builtin_amdgcn_mfma_f32_16x16x32_bf16(a1, bfrag, c[1], 0, 0, 0);
        }
#pragma unroll
        for (int rt = 0; rt < 2; ++rt)
#pragma unroll
            for (int r = 0; r < 4; ++r) {
                int row = rt * 16 + g * 4 + r;
                sPhi[row][f2][half] = c[rt][r] + b2v;
            }
    }
    __syncthreads();

    // ---- P3 setup: Wf fragments + phi hoist (static reg indices) -------
    short8 wfrag0 = load_wffrag(Wf, bf, f2, g);
    short8 wfrag2 = load_wffrag(Wf, bf, 256 + f2, g);
    const float kth = 3.14159265358979323846f / CUTOFF;

    float ph0[8], ph2[8];
#pragma unroll
    for (int rt = 0; rt < 2; ++rt)
#pragma unroll
        for (int r = 0; r < 4; ++r) {
            int j = rt * 16 + g * 4 + r;
            ph0[rt * 4 + r] = sPhi[j][f2][0];
            ph2[rt * 4 + r] = sPhi[j][f2][1];
        }

    // ---- P3: per 8-i chunk: produce rbf_ext + geo, GEMM, consume -------
    for (int ic = 0; ic < 3; ++ic) {
        if (tid < 256) {
            int il = tid >> 5, j = tid & 31;
            int i = ic * 8 + il;
            unsigned pk[16];
#pragma unroll
            for (int q = 0; q < 16; ++q) pk[q] = 0u;
            unsigned gxy = 0u, gz = 0u;
            if (j < M && j != i) {
                float dx = sPos[i][0] - sPos[j][0];
                float dy = sPos[i][1] - sPos[j][1];
                float dz = sPos[i][2] - sPos[j][2];
                float d = sqrtf(dx * dx + dy * dy + dz * dz);
                if (d < CUTOFF) {
                    float inv = 1.0f / d;
                    float s1, c1;
                    __sincosf(kth * d, &s1, &c1);
                    float cc = 2.0f * c1;
                    float vp = s1 * inv;               // sin(1*th)/d
                    float vc = 2.0f * s1 * c1 * inv;   // sin(2*th)/d
                    pk[0] = f2bf(vp) | (f2bf(vc) << 16);
#pragma unroll
                    for (int q = 1; q < 10; ++q) {
                        float v3 = cc * vc - vp;
                        float v4 = cc * v3 - vc;
                        pk[q] = f2bf(v3) | (f2bf(v4) << 16);
                        vp = v3; vc = v4;
                    }
                    pk[10] = 0x3F80u;                  // k=20: mask = bf16(1.0)
                    gxy = f2h(dx * inv) | (f2h(dy * inv) << 16);
                    gz  = f2h(dz * inv);
                }
            }
            short* rp = &sA[(il * 32 + j) * SA_LD];
#pragma unroll
            for (int q = 0; q < 8; ++q)
                *reinterpret_cast<uint2*>(rp + q * 4) = make_uint2(pk[2 * q], pk[2 * q + 1]);
            *reinterpret_cast<uint2*>(&sGeoH[(il * 32 + j) * 4]) = make_uint2(gxy, gz);
        }
        __syncthreads();

        for (int il = 0; il < 8; ++il) {
            const int i = ic * 8 + il;
            float s0 = 0.f, ax = 0.f, ay = 0.f, az = 0.f;
#pragma unroll
            for (int rt = 0; rt < 2; ++rt) {
                short8 afr = load_afrag(sA, il * 32 + rt * 16 + lrow, SA_LD, 0, g);
                f32x4 z4 = {0.f, 0.f, 0.f, 0.f};
                f32x4 c0 = __builtin_amdgcn_mfma_f32_16x16x32_bf16(afr, wfrag0, z4, 0, 0, 0);
                f32x4 c2 = __builtin_amdgcn_mfma_f32_16x16x32_bf16(afr, wfrag2, z4, 0, 0, 0);
#pragma unroll
                for (int r = 0; r < 4; ++r) {
                    int j = rt * 16 + g * 4 + r;
                    uint2 gw = *reinterpret_cast<const uint2*>(&sGeoH[(il * 32 + j) * 4]);
                    float2 xy = __half22float2(__builtin_bit_cast(__half2, gw.x));
                    float gzf = __half2float(__builtin_bit_cast(__half2, gw.y).x);
                    s0 = fmaf(c0[r], ph0[rt * 4 + r], s0);
                    float m2 = c2[r] * ph2[rt * 4 + r];
                    ax = fmaf(m2, xy.x, ax);
                    ay = fmaf(m2, xy.y, ay);
                    az = fmaf(m2, gzf, az);
                }
            }
            s0 += __shfl_xor(s0, 16); s0 += __shfl_xor(s0, 32);
            ax += __shfl_xor(ax, 16); ax += __shfl_xor(ax, 32);
            ay += __shfl_xor(ay, 16); ay += __shfl_xor(ay, 32);
            az += __shfl_xor(az, 16); az += __shfl_xor(az, 32);
            if (lane < 16) {
                const int node = b * M + i;
                const int a = atoms[node];
                float embv = emb[(size_t)a * F + f2];
                float* o = out + (size_t)node * (4 * F);
                o[f2] = embv + s0;
                o[F + 3 * f2 + 0] = ax;
                o[F + 3 * f2 + 1] = ay;
                o[F + 3 * f2 + 2] = az;
            }
        }
        __syncthreads();   // protect sA/sGeoH before next chunk's produce
    }
}

extern "C" void kernel_launch(void* const* d_in, const int* in_sizes, int n_in,
                              void* d_out, int out_size, void* d_ws, size_t ws_size,
                              hipStream_t stream) {
    const int*   atoms = (const int*)d_in[0];
    const float* apos  = (const float*)d_in[1];
    // d_in[2] = graph_indexes (unused; batch structure is the fixed [B,M] layout)
    const float* emb = (const float*)d_in[3];
    const float* W1  = (const float*)d_in[4];
    const float* b1  = (const float*)d_in[5];
    const float* W2  = (const float*)d_in[6];
    const float* b2  = (const float*)d_in[7];
    const float* Wf  = (const float*)d_in[8];
    const float* bf  = (const float*)d_in[9];
    float* out = (float*)d_out;

    painn_kernel<<<B, 512, 0, stream>>>(atoms, apos, emb, W1, b1, W2, b2, Wf, bf, out);
}